// Round 2
// baseline (2629.341 us; speedup 1.0000x reference)
//
#include <hip/hip_runtime.h>
#include <stdint.h>

#define BATCH 8
#define CIN   128
#define HH    192
#define WW    192
#define HW    (HH*WW)       // 36864
#define PXB   576           // (HW/64) pixel-tiles per batch

typedef _Float16 half_t;
typedef _Float16 f16x8 __attribute__((ext_vector_type(8)));
typedef float    f32x4 __attribute__((ext_vector_type(4)));

// ---------------------------------------------------------------------------
// Fused LayerNorm(channel) + 1x1 conv (GEMM) via MFMA f16.
// Grid: nb*576 blocks of 256 threads; tile = 64 px x 64 out-ch (looped).
// ---------------------------------------------------------------------------
template<int OC>
__global__ __launch_bounds__(256)
void ln_gemm_kernel(const float* __restrict__ x,     // offset to batch b0
                    const float* __restrict__ lnw, const float* __restrict__ lnb,
                    const float* __restrict__ w,   const float* __restrict__ wb,
                    half_t* __restrict__ out)         // pass-local
{
    __shared__ half_t As[64][136];
    __shared__ half_t Wsh[64][136];
    __shared__ float  redA[4][64];
    __shared__ float  redB[4][64];
    __shared__ float  mu_s[64], rs_s[64];

    const int tid = threadIdx.x;
    const int px  = tid & 63;
    const int g   = tid >> 6;
    const int l   = tid & 63;
    const int wv  = tid >> 6;

    const long p0  = (long)blockIdx.x * 64;
    const int  b   = (int)(p0 / HW);          // local batch
    const int  hw0 = (int)(p0 - (long)b * HW);

    const float* xb = x + (size_t)b * CIN * HW + hw0 + px;
    float vals[32];
    float s1 = 0.f, s2 = 0.f;
#pragma unroll
    for (int j = 0; j < 32; ++j) {
        float v = xb[(size_t)(g * 32 + j) * HW];
        vals[j] = v; s1 += v; s2 += v * v;
    }
    redA[g][px] = s1; redB[g][px] = s2;
    __syncthreads();
    if (tid < 64) {
        float su = redA[0][tid] + redA[1][tid] + redA[2][tid] + redA[3][tid];
        float sq = redB[0][tid] + redB[1][tid] + redB[2][tid] + redB[3][tid];
        float mu  = su * (1.f / 128.f);
        float var = sq * (1.f / 128.f) - mu * mu;
        mu_s[tid] = mu;
        rs_s[tid] = rsqrtf(var + 1e-5f);
    }
    __syncthreads();
    {
        float mu = mu_s[px], rs = rs_s[px];
#pragma unroll
        for (int j = 0; j < 32; ++j) {
            int c = g * 32 + j;
            float a = (vals[j] - mu) * rs * lnw[c] + lnb[c];
            As[px][c] = (half_t)a;
        }
    }

    for (int nc = 0; nc < OC / 64; ++nc) {
        const int n0 = nc * 64;
#pragma unroll
        for (int i = 0; i < 8; ++i) {
            int f  = i * 256 + tid;       // 2048 float4
            int n  = f >> 5;
            int kq = (f & 31) << 2;
            const float4 wvv = *(const float4*)&w[(size_t)(n0 + n) * CIN + kq];
            Wsh[n][kq]     = (half_t)wvv.x;
            Wsh[n][kq + 1] = (half_t)wvv.y;
            Wsh[n][kq + 2] = (half_t)wvv.z;
            Wsh[n][kq + 3] = (half_t)wvv.w;
        }
        __syncthreads();

        f16x8 af[4];
#pragma unroll
        for (int kt = 0; kt < 4; ++kt)
            af[kt] = *(const f16x8*)&Wsh[wv * 16 + (l & 15)][kt * 32 + (l >> 4) * 8];

#pragma unroll
        for (int pt = 0; pt < 4; ++pt) {
            f32x4 acc = {0.f, 0.f, 0.f, 0.f};
#pragma unroll
            for (int kt = 0; kt < 4; ++kt) {
                f16x8 bfv = *(const f16x8*)&As[pt * 16 + (l & 15)][kt * 32 + (l >> 4) * 8];
                acc = __builtin_amdgcn_mfma_f32_16x16x32_f16(af[kt], bfv, acc, 0, 0, 0);
            }
#pragma unroll
            for (int r = 0; r < 4; ++r) {
                int n  = n0 + wv * 16 + (l >> 4) * 4 + r;
                int po = pt * 16 + (l & 15);
                float v = acc[r] + wb[n];
                out[((size_t)b * OC + n) * HW + hw0 + po] = (half_t)v;
            }
        }
        __syncthreads();
    }
}

// ---------------------------------------------------------------------------
// Depthwise 3x3 for the v half of kv1 only. Grid: nb*256*144.
// ---------------------------------------------------------------------------
__global__ __launch_bounds__(256)
void vdw_kernel(const half_t* __restrict__ kv1, const float* __restrict__ wt,
                const float* __restrict__ bias, half_t* __restrict__ vd)
{
    int bid = blockIdx.x;
    int lc  = bid / 144;                        // lb*256 + c
    int hw  = (bid % 144) * 256 + threadIdx.x;
    int lb  = lc >> 8;
    int c   = lc & 255;
    int h   = hw / WW, w0 = hw % WW;
    const half_t* ip = kv1 + ((size_t)lb * 512 + 256 + c) * HW;
    const float*  wp = wt + (256 + c) * 9;
    float acc = bias[256 + c];
#pragma unroll
    for (int dy = -1; dy <= 1; ++dy) {
        int hh = h + dy;
        if (hh < 0 || hh >= HH) continue;
#pragma unroll
        for (int dx = -1; dx <= 1; ++dx) {
            int ww2 = w0 + dx;
            if (ww2 < 0 || ww2 >= WW) continue;
            acc += (float)ip[hh * WW + ww2] * wp[(dy + 1) * 3 + (dx + 1)];
        }
    }
    vd[((size_t)lb * 256 + c) * HW + hw] = (half_t)acc;
}

// ---------------------------------------------------------------------------
// Fused: dwconv3x3(q1), dwconv3x3(k1) via 10x10 halo in LDS, then per-patch
// 8x8 circular convolution. Block = one (patch, 32-channel chunk).
// Grid: nb * 24*24 * 8. Thread = (ch, row).
// ---------------------------------------------------------------------------
__global__ __launch_bounds__(256)
void corr_fused_kernel(const half_t* __restrict__ q1, const half_t* __restrict__ kv1,
                       const float* __restrict__ qw, const float* __restrict__ qb,
                       const float* __restrict__ kw, const float* __restrict__ kb,
                       half_t* __restrict__ corr)
{
    __shared__ half_t qh[32][10][12];
    __shared__ half_t kh[32][10][12];
    __shared__ float  qs[32 * 68];     // post-dw q, [ch][u*8+x]
    __shared__ float  k2[32 * 164];    // post-dw k doubled rows, stride 20

    int bid = blockIdx.x;
    int pw = bid % 24; int t1 = bid / 24;
    int ck = t1 % 8;   int t2 = t1 / 8;
    int ph = t2 % 24;  int lb = t2 / 24;
    int c0 = ck * 32;
    int tid = threadIdx.x;
    int ch  = tid >> 3;
    int r   = tid & 7;

    // ---- halo loads (rows hr = r, plus 8+r for r<2), cols -1..+8 ----
    const half_t* qp = q1  + ((size_t)lb * 256 + c0 + ch) * HW;
    const half_t* kp = kv1 + ((size_t)lb * 512 + c0 + ch) * HW;   // k = ch 0..255
    {
        int nrow = (r < 2) ? 2 : 1;
        for (int rr = 0; rr < nrow; ++rr) {
            int hr = (rr == 0) ? r : (8 + r);
            int gh = ph * 8 - 1 + hr;
            bool hok = (gh >= 0 && gh < HH);
#pragma unroll
            for (int hc = 0; hc < 10; ++hc) {
                int gw = pw * 8 - 1 + hc;
                bool ok = hok && gw >= 0 && gw < WW;
                qh[ch][hr][hc] = ok ? qp[gh * WW + gw] : (half_t)0.f;
                kh[ch][hr][hc] = ok ? kp[gh * WW + gw] : (half_t)0.f;
            }
        }
    }
    __syncthreads();

    // ---- depthwise 3x3 on the halo, thread (ch, u=r) does one output row ----
    {
        const float* wq = qw + (size_t)(c0 + ch) * 9;
        const float* wk = kw + (size_t)(c0 + ch) * 9;
        float aq[8], ak[8];
        float bq = qb[c0 + ch], bk = kb[c0 + ch];
#pragma unroll
        for (int x = 0; x < 8; ++x) { aq[x] = bq; ak[x] = bk; }
#pragma unroll
        for (int dy = 0; dy < 3; ++dy) {
#pragma unroll
            for (int dx = 0; dx < 3; ++dx) {
                float wwq = wq[dy * 3 + dx];
                float wwk = wk[dy * 3 + dx];
#pragma unroll
                for (int x = 0; x < 8; ++x) {
                    aq[x] += (float)qh[ch][r + dy][x + dx] * wwq;
                    ak[x] += (float)kh[ch][r + dy][x + dx] * wwk;
                }
            }
        }
        float* qrow = &qs[ch * 68 + r * 8];
        float* krow = &k2[ch * 164 + r * 20];
#pragma unroll
        for (int x = 0; x < 8; ++x) {
            qrow[x]     = aq[x];
            krow[x]     = ak[x];
            krow[x + 8] = ak[x];
        }
    }
    __syncthreads();

    // ---- circular convolution: corr[u,v] = sum_{s,t} q[s,t] k[(u-s)&7,(v-t)&7]
    int u = r;
    float acc[8];
#pragma unroll
    for (int v = 0; v < 8; ++v) acc[v] = 0.f;
    const float* kbase = &k2[ch * 164];
    const float* qbase = &qs[ch * 68];
#pragma unroll
    for (int s = 0; s < 8; ++s) {
        int row = (u - s) & 7;
        const float* krp = kbase + row * 20;
        float kr[16] __attribute__((aligned(16)));
        *(float4*)&kr[0]  = *(const float4*)&krp[0];
        *(float4*)&kr[4]  = *(const float4*)&krp[4];
        *(float4*)&kr[8]  = *(const float4*)&krp[8];
        *(float4*)&kr[12] = *(const float4*)&krp[12];
        float qr[8] __attribute__((aligned(16)));
        *(float4*)&qr[0] = *(const float4*)&qbase[s * 8];
        *(float4*)&qr[4] = *(const float4*)&qbase[s * 8 + 4];
#pragma unroll
        for (int t = 0; t < 8; ++t)
#pragma unroll
            for (int v = 0; v < 8; ++v)
                acc[v] += qr[t] * kr[8 - t + v];
    }
    f16x8 ov;
#pragma unroll
    for (int v = 0; v < 8; ++v) ov[v] = (half_t)acc[v];
    size_t ooff = ((size_t)lb * 256 + c0 + ch) * HW + (ph * 8 + u) * WW + pw * 8;
    *(f16x8*)(corr + ooff) = ov;
}

// ---------------------------------------------------------------------------
// Fused LN(corr)*vd + 1x1 proj GEMM (K=256 split in 2, N=128) -> f32 out.
// LDS: As 17.4K + Wsh 34.8K + red 2.5K = 54.8K.
// ---------------------------------------------------------------------------
__global__ __launch_bounds__(256)
void proj_kernel(const half_t* __restrict__ corr, const half_t* __restrict__ vd,
                 const float* __restrict__ lnw, const float* __restrict__ lnb,
                 const float* __restrict__ w,   const float* __restrict__ wb,
                 float* __restrict__ out)       // offset to batch b0
{
    __shared__ half_t As[64][136];
    __shared__ half_t Wsh[128][136];
    __shared__ float  redA[4][64];
    __shared__ float  redB[4][64];
    __shared__ float  mu_s[64], rs_s[64];

    const int tid = threadIdx.x;
    const int px  = tid & 63;
    const int g   = tid >> 6;
    const int l   = tid & 63;
    const int wv  = tid >> 6;

    const long p0  = (long)blockIdx.x * 64;
    const int  lb  = (int)(p0 / HW);
    const int  hw0 = (int)(p0 - (long)lb * HW);

    const half_t* cb = corr + (size_t)lb * 256 * HW + hw0 + px;
    const half_t* vb = vd   + (size_t)lb * 256 * HW + hw0 + px;

    float s1 = 0.f, s2 = 0.f;
#pragma unroll 8
    for (int j = 0; j < 64; ++j) {
        float cv = (float)cb[(size_t)(g * 64 + j) * HW];
        s1 += cv; s2 += cv * cv;
    }
    redA[g][px] = s1; redB[g][px] = s2;
    __syncthreads();
    if (tid < 64) {
        float su = redA[0][tid] + redA[1][tid] + redA[2][tid] + redA[3][tid];
        float sq = redB[0][tid] + redB[1][tid] + redB[2][tid] + redB[3][tid];
        float mu  = su * (1.f / 256.f);
        float var = sq * (1.f / 256.f) - mu * mu;
        mu_s[tid] = mu;
        rs_s[tid] = rsqrtf(var + 1e-5f);
    }
    __syncthreads();
    const float mu = mu_s[px], rs = rs_s[px];

    f32x4 acc[2][4];
#pragma unroll
    for (int nt = 0; nt < 2; ++nt)
#pragma unroll
        for (int pt = 0; pt < 4; ++pt) acc[nt][pt] = {0.f, 0.f, 0.f, 0.f};

    for (int kc = 0; kc < 2; ++kc) {
        // fill As with K-half of LN(corr)*vd
#pragma unroll 4
        for (int j = 0; j < 32; ++j) {
            int cl = g * 32 + j;
            int c  = kc * 128 + cl;
            float cv = (float)cb[(size_t)c * HW];
            float vv = (float)vb[(size_t)c * HW];
            As[px][cl] = (half_t)(((cv - mu) * rs * lnw[c] + lnb[c]) * vv);
        }
        // stage K-half of weights: 128 n x 128 k
#pragma unroll
        for (int i = 0; i < 16; ++i) {
            int f  = i * 256 + tid;     // 4096 float4
            int n  = f >> 5;
            int kq = (f & 31) << 2;
            const float4 wvv = *(const float4*)&w[(size_t)n * 256 + kc * 128 + kq];
            Wsh[n][kq]     = (half_t)wvv.x;
            Wsh[n][kq + 1] = (half_t)wvv.y;
            Wsh[n][kq + 2] = (half_t)wvv.z;
            Wsh[n][kq + 3] = (half_t)wvv.w;
        }
        __syncthreads();

#pragma unroll
        for (int nt = 0; nt < 2; ++nt) {
            f16x8 af[4];
#pragma unroll
            for (int kt = 0; kt < 4; ++kt)
                af[kt] = *(const f16x8*)&Wsh[wv * 32 + nt * 16 + (l & 15)][kt * 32 + (l >> 4) * 8];
#pragma unroll
            for (int pt = 0; pt < 4; ++pt) {
#pragma unroll
                for (int kt = 0; kt < 4; ++kt) {
                    f16x8 bfv = *(const f16x8*)&As[pt * 16 + (l & 15)][kt * 32 + (l >> 4) * 8];
                    acc[nt][pt] = __builtin_amdgcn_mfma_f32_16x16x32_f16(af[kt], bfv, acc[nt][pt], 0, 0, 0);
                }
            }
        }
        __syncthreads();
    }

#pragma unroll
    for (int nt = 0; nt < 2; ++nt)
#pragma unroll
        for (int pt = 0; pt < 4; ++pt)
#pragma unroll
            for (int r = 0; r < 4; ++r) {
                int n  = wv * 32 + nt * 16 + (l >> 4) * 4 + r;
                int po = pt * 16 + (l & 15);
                out[((size_t)lb * 128 + n) * HW + hw0 + po] = acc[nt][pt][r] + wb[n];
            }
}

// ---------------------------------------------------------------------------
extern "C" void kernel_launch(void* const* d_in, const int* in_sizes, int n_in,
                              void* d_out, int out_size, void* d_ws, size_t ws_size,
                              hipStream_t stream)
{
    const float* x        = (const float*)d_in[0];
    const float* evt      = (const float*)d_in[1];
    const float* ln_img_w = (const float*)d_in[2];
    const float* ln_img_b = (const float*)d_in[3];
    const float* ln_evt_w = (const float*)d_in[4];
    const float* ln_evt_b = (const float*)d_in[5];
    const float* q_w      = (const float*)d_in[6];
    const float* q_b      = (const float*)d_in[7];
    const float* q_dw_w   = (const float*)d_in[8];
    const float* q_dw_b   = (const float*)d_in[9];
    const float* kv_w     = (const float*)d_in[10];
    const float* kv_b     = (const float*)d_in[11];
    const float* kv_dw_w  = (const float*)d_in[12];
    const float* kv_dw_b  = (const float*)d_in[13];
    const float* ln_corr_w= (const float*)d_in[14];
    const float* ln_corr_b= (const float*)d_in[15];
    const float* proj_w   = (const float*)d_in[16];
    const float* proj_b   = (const float*)d_in[17];
    float* out = (float*)d_out;

    // per-batch scratch need (halves): q1 256*HW, kv1 512*HW, vd 256*HW, corr 256*HW
    const size_t per_b = (size_t)(256 + 512 + 256 + 256) * HW * sizeof(half_t); // 94,371,840 B
    int PB = 1;
    if      (ws_size >= 8 * per_b) PB = 8;
    else if (ws_size >= 4 * per_b) PB = 4;
    else if (ws_size >= 2 * per_b) PB = 2;

    half_t* q1   = (half_t*)d_ws;
    half_t* kv1  = q1  + (size_t)PB * 256 * HW;
    half_t* vd   = kv1 + (size_t)PB * 512 * HW;
    half_t* corr = vd  + (size_t)PB * 256 * HW;

    dim3 blk(256);
    for (int b0 = 0; b0 < BATCH; b0 += PB) {
        int nb = PB;
        ln_gemm_kernel<256><<<nb * PXB, blk, 0, stream>>>(
            x + (size_t)b0 * CIN * HW, ln_img_w, ln_img_b, q_w, q_b, q1);
        ln_gemm_kernel<512><<<nb * PXB, blk, 0, stream>>>(
            evt + (size_t)b0 * CIN * HW, ln_evt_w, ln_evt_b, kv_w, kv_b, kv1);
        vdw_kernel<<<nb * 256 * 144, blk, 0, stream>>>(kv1, kv_dw_w, kv_dw_b, vd);
        corr_fused_kernel<<<nb * 24 * 24 * 8, blk, 0, stream>>>(
            q1, kv1, q_dw_w, q_dw_b, kv_dw_w, kv_dw_b, corr);
        proj_kernel<<<nb * PXB, blk, 0, stream>>>(
            corr, vd, ln_corr_w, ln_corr_b, proj_w, proj_b,
            out + (size_t)b0 * 128 * HW);
    }
}

// Round 3
// 1205.447 us; speedup vs baseline: 2.1812x; 2.1812x over previous
//
#include <hip/hip_runtime.h>
#include <stdint.h>

#define BATCH 8
#define CIN   128
#define HH    192
#define WW    192
#define HW    (HH*WW)       // 36864
#define PXB   576           // (HW/64) pixel-tiles per batch
#define CH    2             // channels per corr block

typedef _Float16 half_t;
typedef _Float16 f16x8 __attribute__((ext_vector_type(8)));
typedef float    f32x4 __attribute__((ext_vector_type(4)));

// ---------------------------------------------------------------------------
// Fused LayerNorm(channel) + 1x1 conv (GEMM) via MFMA f16.
// ---------------------------------------------------------------------------
template<int OC>
__global__ __launch_bounds__(256)
void ln_gemm_kernel(const float* __restrict__ x,
                    const float* __restrict__ lnw, const float* __restrict__ lnb,
                    const float* __restrict__ w,   const float* __restrict__ wb,
                    half_t* __restrict__ out)
{
    __shared__ __attribute__((aligned(16))) half_t As[64][136];
    __shared__ __attribute__((aligned(16))) half_t Wsh[64][136];
    __shared__ float  redA[4][64];
    __shared__ float  redB[4][64];
    __shared__ float  mu_s[64], rs_s[64];

    const int tid = threadIdx.x;
    const int px  = tid & 63;
    const int g   = tid >> 6;
    const int l   = tid & 63;
    const int wv  = tid >> 6;

    const long p0  = (long)blockIdx.x * 64;
    const int  b   = (int)(p0 / HW);
    const int  hw0 = (int)(p0 - (long)b * HW);

    const float* xb = x + (size_t)b * CIN * HW + hw0 + px;
    float vals[32];
    float s1 = 0.f, s2 = 0.f;
#pragma unroll
    for (int j = 0; j < 32; ++j) {
        float v = xb[(size_t)(g * 32 + j) * HW];
        vals[j] = v; s1 += v; s2 += v * v;
    }
    redA[g][px] = s1; redB[g][px] = s2;
    __syncthreads();
    if (tid < 64) {
        float su = redA[0][tid] + redA[1][tid] + redA[2][tid] + redA[3][tid];
        float sq = redB[0][tid] + redB[1][tid] + redB[2][tid] + redB[3][tid];
        float mu  = su * (1.f / 128.f);
        float var = sq * (1.f / 128.f) - mu * mu;
        mu_s[tid] = mu;
        rs_s[tid] = rsqrtf(var + 1e-5f);
    }
    __syncthreads();
    {
        float mu = mu_s[px], rs = rs_s[px];
#pragma unroll
        for (int j = 0; j < 32; ++j) {
            int c = g * 32 + j;
            float a = (vals[j] - mu) * rs * lnw[c] + lnb[c];
            As[px][c] = (half_t)a;
        }
    }

    for (int nc = 0; nc < OC / 64; ++nc) {
        const int n0 = nc * 64;
#pragma unroll
        for (int i = 0; i < 8; ++i) {
            int f  = i * 256 + tid;
            int n  = f >> 5;
            int kq = (f & 31) << 2;
            const float4 wvv = *(const float4*)&w[(size_t)(n0 + n) * CIN + kq];
            Wsh[n][kq]     = (half_t)wvv.x;
            Wsh[n][kq + 1] = (half_t)wvv.y;
            Wsh[n][kq + 2] = (half_t)wvv.z;
            Wsh[n][kq + 3] = (half_t)wvv.w;
        }
        __syncthreads();

        f16x8 af[4];
#pragma unroll
        for (int kt = 0; kt < 4; ++kt)
            af[kt] = *(const f16x8*)&Wsh[wv * 16 + (l & 15)][kt * 32 + (l >> 4) * 8];

#pragma unroll
        for (int pt = 0; pt < 4; ++pt) {
            f32x4 acc = {0.f, 0.f, 0.f, 0.f};
#pragma unroll
            for (int kt = 0; kt < 4; ++kt) {
                f16x8 bfv = *(const f16x8*)&As[pt * 16 + (l & 15)][kt * 32 + (l >> 4) * 8];
                acc = __builtin_amdgcn_mfma_f32_16x16x32_f16(af[kt], bfv, acc, 0, 0, 0);
            }
#pragma unroll
            for (int r = 0; r < 4; ++r) {
                int n  = n0 + wv * 16 + (l >> 4) * 4 + r;
                int po = pt * 16 + (l & 15);
                float v = acc[r] + wb[n];
                out[((size_t)b * OC + n) * HW + hw0 + po] = (half_t)v;
            }
        }
        __syncthreads();
    }
}

// ---------------------------------------------------------------------------
// Depthwise 3x3 for the v half of kv1 only.
// ---------------------------------------------------------------------------
__global__ __launch_bounds__(256)
void vdw_kernel(const half_t* __restrict__ kv1, const float* __restrict__ wt,
                const float* __restrict__ bias, half_t* __restrict__ vd)
{
    int bid = blockIdx.x;
    int lc  = bid / 144;
    int hw  = (bid % 144) * 256 + threadIdx.x;
    int lb  = lc >> 8;
    int c   = lc & 255;
    int h   = hw / WW, w0 = hw % WW;
    const half_t* ip = kv1 + ((size_t)lb * 512 + 256 + c) * HW;
    const float*  wp = wt + (256 + c) * 9;
    float acc = bias[256 + c];
#pragma unroll
    for (int dy = -1; dy <= 1; ++dy) {
        int hh = h + dy;
        if (hh < 0 || hh >= HH) continue;
#pragma unroll
        for (int dx = -1; dx <= 1; ++dx) {
            int ww2 = w0 + dx;
            if (ww2 < 0 || ww2 >= WW) continue;
            acc += (float)ip[hh * WW + ww2] * wp[(dy + 1) * 3 + (dx + 1)];
        }
    }
    vd[((size_t)lb * 256 + c) * HW + hw] = (half_t)acc;
}

// ---------------------------------------------------------------------------
// Strip-based fused dwconv(q) + dwconv(k) + per-patch 8x8 circular conv.
// Block = (lb, patch-row ph, CH channels). Full-width strip in LDS:
//   stage A: coalesced f16x8 loads of 10 rows x 192 cols (+ zeroed col halo)
//   stage B: dwconv3x3 -> qd/kd (f16, col j = global col j)
//   stage C: circular conv per (c, pw, u), b128 LDS reads, static unroll.
// LDS = 29.3 KB.
// ---------------------------------------------------------------------------
__global__ __launch_bounds__(256)
void corr_strip_kernel(const half_t* __restrict__ q1, const half_t* __restrict__ kv1,
                       const float* __restrict__ qw, const float* __restrict__ qb,
                       const float* __restrict__ kw, const float* __restrict__ kb,
                       half_t* __restrict__ corr)
{
    __shared__ __attribute__((aligned(16))) half_t qraw[CH][10][208];
    __shared__ __attribute__((aligned(16))) half_t kraw[CH][10][208];
    __shared__ __attribute__((aligned(16))) half_t qd[CH][8][208];
    __shared__ __attribute__((aligned(16))) half_t kd[CH][8][208];

    const int bid = blockIdx.x;
    const int cg  = bid & 127;          // 128 channel-groups of CH=2
    const int ph  = (bid >> 7) % 24;
    const int lb  = (bid >> 7) / 24;
    const int c0  = cg * CH;
    const int tid = threadIdx.x;

    // ---- zero the column-halo slots (cols 0..7 and 200..207 of each row) ----
    if (tid < 80) {
        int side = tid & 1;
        int row  = (tid >> 1) % 10;
        int a    = tid / 20;            // 0..3 : q ch0, q ch1, k ch0, k ch1
        int ch   = a & 1;
        half_t* base = (a < 2) ? &qraw[ch][row][0] : &kraw[ch][row][0];
        f16x8 z = {};
        *(f16x8*)&base[side ? 200 : 0] = z;
    }

    // ---- stage A: coalesced strip loads (rows ph*8-1 .. ph*8+8) ----
    for (int i = 0; i < 4; ++i) {
        int idx = tid + 256 * i;        // 960 vector-loads total
        if (idx >= 960) break;
        int vec = idx % 24;             // col group (8 cols)
        int row = (idx / 24) % 10;
        int a   = idx / 240;            // 0..3
        int ch  = a & 1;
        int gh  = ph * 8 - 1 + row;
        f16x8 v = {};
        if (gh >= 0 && gh < HH) {
            const half_t* src = (a < 2)
                ? q1  + ((size_t)lb * 256 + c0 + ch) * HW
                : kv1 + ((size_t)lb * 512 + c0 + ch) * HW;   // k = ch 0..255
            v = *(const f16x8*)&src[(size_t)gh * WW + vec * 8];
        }
        half_t* dst = (a < 2) ? &qraw[ch][row][8 + vec * 8]
                              : &kraw[ch][row][8 + vec * 8];
        *(f16x8*)dst = v;
    }
    __syncthreads();

    // ---- stage B: depthwise 3x3 -> qd/kd ----
#pragma unroll
    for (int i = 0; i < 3; ++i) {
        int unit = tid + 256 * i;       // 768 units: (arr,ch,u,xg)
        int xg = unit % 24;
        int u  = (unit / 24) % 8;
        int a  = unit / 192;            // 0..3
        int ch = a & 1;
        bool isq = (a < 2);
        const half_t (*raw)[208] = isq ? qraw[ch] : kraw[ch];
        const float* wt = (isq ? qw : kw) + (size_t)(c0 + ch) * 9;
        float bias = (isq ? qb : kb)[c0 + ch];
        int x0 = xg * 8;
        float r0[10], r1[10], r2[10];
#pragma unroll
        for (int j = 0; j < 10; ++j) {
            r0[j] = (float)raw[u + 0][7 + x0 + j];
            r1[j] = (float)raw[u + 1][7 + x0 + j];
            r2[j] = (float)raw[u + 2][7 + x0 + j];
        }
        float acc[8];
#pragma unroll
        for (int xx = 0; xx < 8; ++xx) acc[xx] = bias;
#pragma unroll
        for (int dx = 0; dx < 3; ++dx) {
            float w0 = wt[dx], w1 = wt[3 + dx], w2 = wt[6 + dx];
#pragma unroll
            for (int xx = 0; xx < 8; ++xx) {
                acc[xx] += r0[xx + dx] * w0 + r1[xx + dx] * w1 + r2[xx + dx] * w2;
            }
        }
        f16x8 o;
#pragma unroll
        for (int xx = 0; xx < 8; ++xx) o[xx] = (half_t)acc[xx];
        half_t* dst = isq ? &qd[ch][u][x0] : &kd[ch][u][x0];
        *(f16x8*)dst = o;
    }
    __syncthreads();

    // ---- stage C: per-patch circular conv ----
    for (int i = 0; i < 2; ++i) {
        int unit = tid + 256 * i;       // 384 units: (c, pw, u)
        if (unit >= 384) break;
        int c   = unit / 192;
        int rem = unit % 192;
        int pw  = rem >> 3;
        int u   = rem & 7;
        float acc[8];
#pragma unroll
        for (int v = 0; v < 8; ++v) acc[v] = 0.f;
#pragma unroll
        for (int s = 0; s < 8; ++s) {
            f16x8 qv8 = *(const f16x8*)&qd[c][s][pw * 8];
            f16x8 kv8 = *(const f16x8*)&kd[c][(u - s) & 7][pw * 8];
            float qv[8], kr2[16];
#pragma unroll
            for (int t = 0; t < 8; ++t) {
                qv[t] = (float)qv8[t];
                float kvf = (float)kv8[t];
                kr2[t] = kvf; kr2[t + 8] = kvf;
            }
#pragma unroll
            for (int t = 0; t < 8; ++t)
#pragma unroll
                for (int v = 0; v < 8; ++v)
                    acc[v] += qv[t] * kr2[8 - t + v];
        }
        f16x8 ov;
#pragma unroll
        for (int v = 0; v < 8; ++v) ov[v] = (half_t)acc[v];
        *(f16x8*)&corr[((size_t)lb * 256 + c0 + c) * HW + (size_t)(ph * 8 + u) * WW + pw * 8] = ov;
    }
}

// ---------------------------------------------------------------------------
// Fused LN(corr)*vd + 1x1 proj GEMM (K=256 split in 2, N=128) -> f32 out.
// ---------------------------------------------------------------------------
__global__ __launch_bounds__(256)
void proj_kernel(const half_t* __restrict__ corr, const half_t* __restrict__ vd,
                 const float* __restrict__ lnw, const float* __restrict__ lnb,
                 const float* __restrict__ w,   const float* __restrict__ wb,
                 float* __restrict__ out)
{
    __shared__ __attribute__((aligned(16))) half_t As[64][136];
    __shared__ __attribute__((aligned(16))) half_t Wsh[128][136];
    __shared__ float  redA[4][64];
    __shared__ float  redB[4][64];
    __shared__ float  mu_s[64], rs_s[64];

    const int tid = threadIdx.x;
    const int px  = tid & 63;
    const int g   = tid >> 6;
    const int l   = tid & 63;
    const int wv  = tid >> 6;

    const long p0  = (long)blockIdx.x * 64;
    const int  lb  = (int)(p0 / HW);
    const int  hw0 = (int)(p0 - (long)lb * HW);

    const half_t* cb = corr + (size_t)lb * 256 * HW + hw0 + px;
    const half_t* vb = vd   + (size_t)lb * 256 * HW + hw0 + px;

    float s1 = 0.f, s2 = 0.f;
#pragma unroll 8
    for (int j = 0; j < 64; ++j) {
        float cv = (float)cb[(size_t)(g * 64 + j) * HW];
        s1 += cv; s2 += cv * cv;
    }
    redA[g][px] = s1; redB[g][px] = s2;
    __syncthreads();
    if (tid < 64) {
        float su = redA[0][tid] + redA[1][tid] + redA[2][tid] + redA[3][tid];
        float sq = redB[0][tid] + redB[1][tid] + redB[2][tid] + redB[3][tid];
        float mu  = su * (1.f / 256.f);
        float var = sq * (1.f / 256.f) - mu * mu;
        mu_s[tid] = mu;
        rs_s[tid] = rsqrtf(var + 1e-5f);
    }
    __syncthreads();
    const float mu = mu_s[px], rs = rs_s[px];

    f32x4 acc[2][4];
#pragma unroll
    for (int nt = 0; nt < 2; ++nt)
#pragma unroll
        for (int pt = 0; pt < 4; ++pt) acc[nt][pt] = {0.f, 0.f, 0.f, 0.f};

    for (int kc = 0; kc < 2; ++kc) {
#pragma unroll 4
        for (int j = 0; j < 32; ++j) {
            int cl = g * 32 + j;
            int c  = kc * 128 + cl;
            float cv = (float)cb[(size_t)c * HW];
            float vv = (float)vb[(size_t)c * HW];
            As[px][cl] = (half_t)(((cv - mu) * rs * lnw[c] + lnb[c]) * vv);
        }
#pragma unroll
        for (int i = 0; i < 16; ++i) {
            int f  = i * 256 + tid;
            int n  = f >> 5;
            int kq = (f & 31) << 2;
            const float4 wvv = *(const float4*)&w[(size_t)n * 256 + kc * 128 + kq];
            Wsh[n][kq]     = (half_t)wvv.x;
            Wsh[n][kq + 1] = (half_t)wvv.y;
            Wsh[n][kq + 2] = (half_t)wvv.z;
            Wsh[n][kq + 3] = (half_t)wvv.w;
        }
        __syncthreads();

#pragma unroll
        for (int nt = 0; nt < 2; ++nt) {
            f16x8 af[4];
#pragma unroll
            for (int kt = 0; kt < 4; ++kt)
                af[kt] = *(const f16x8*)&Wsh[wv * 32 + nt * 16 + (l & 15)][kt * 32 + (l >> 4) * 8];
#pragma unroll
            for (int pt = 0; pt < 4; ++pt) {
#pragma unroll
                for (int kt = 0; kt < 4; ++kt) {
                    f16x8 bfv = *(const f16x8*)&As[pt * 16 + (l & 15)][kt * 32 + (l >> 4) * 8];
                    acc[nt][pt] = __builtin_amdgcn_mfma_f32_16x16x32_f16(af[kt], bfv, acc[nt][pt], 0, 0, 0);
                }
            }
        }
        __syncthreads();
    }

#pragma unroll
    for (int nt = 0; nt < 2; ++nt)
#pragma unroll
        for (int pt = 0; pt < 4; ++pt)
#pragma unroll
            for (int r = 0; r < 4; ++r) {
                int n  = wv * 32 + nt * 16 + (l >> 4) * 4 + r;
                int po = pt * 16 + (l & 15);
                out[((size_t)lb * 128 + n) * HW + hw0 + po] = acc[nt][pt][r] + wb[n];
            }
}

// ---------------------------------------------------------------------------
extern "C" void kernel_launch(void* const* d_in, const int* in_sizes, int n_in,
                              void* d_out, int out_size, void* d_ws, size_t ws_size,
                              hipStream_t stream)
{
    const float* x        = (const float*)d_in[0];
    const float* evt      = (const float*)d_in[1];
    const float* ln_img_w = (const float*)d_in[2];
    const float* ln_img_b = (const float*)d_in[3];
    const float* ln_evt_w = (const float*)d_in[4];
    const float* ln_evt_b = (const float*)d_in[5];
    const float* q_w      = (const float*)d_in[6];
    const float* q_b      = (const float*)d_in[7];
    const float* q_dw_w   = (const float*)d_in[8];
    const float* q_dw_b   = (const float*)d_in[9];
    const float* kv_w     = (const float*)d_in[10];
    const float* kv_b     = (const float*)d_in[11];
    const float* kv_dw_w  = (const float*)d_in[12];
    const float* kv_dw_b  = (const float*)d_in[13];
    const float* ln_corr_w= (const float*)d_in[14];
    const float* ln_corr_b= (const float*)d_in[15];
    const float* proj_w   = (const float*)d_in[16];
    const float* proj_b   = (const float*)d_in[17];
    float* out = (float*)d_out;

    const size_t per_b = (size_t)(256 + 512 + 256 + 256) * HW * sizeof(half_t); // 94.4 MB
    int PB = 1;
    if      (ws_size >= 8 * per_b) PB = 8;
    else if (ws_size >= 4 * per_b) PB = 4;
    else if (ws_size >= 2 * per_b) PB = 2;

    half_t* q1   = (half_t*)d_ws;
    half_t* kv1  = q1  + (size_t)PB * 256 * HW;
    half_t* vd   = kv1 + (size_t)PB * 512 * HW;
    half_t* corr = vd  + (size_t)PB * 256 * HW;

    dim3 blk(256);
    for (int b0 = 0; b0 < BATCH; b0 += PB) {
        int nb = PB;
        ln_gemm_kernel<256><<<nb * PXB, blk, 0, stream>>>(
            x + (size_t)b0 * CIN * HW, ln_img_w, ln_img_b, q_w, q_b, q1);
        ln_gemm_kernel<512><<<nb * PXB, blk, 0, stream>>>(
            evt + (size_t)b0 * CIN * HW, ln_evt_w, ln_evt_b, kv_w, kv_b, kv1);
        vdw_kernel<<<nb * 256 * 144, blk, 0, stream>>>(kv1, kv_dw_w, kv_dw_b, vd);
        corr_strip_kernel<<<nb * 24 * 128, blk, 0, stream>>>(
            q1, kv1, q_dw_w, q_dw_b, kv_dw_w, kv_dw_b, corr);
        proj_kernel<<<nb * PXB, blk, 0, stream>>>(
            corr, vd, ln_corr_w, ln_corr_b, proj_w, proj_b,
            out + (size_t)b0 * 128 * HW);
    }
}

// Round 4
// 868.786 us; speedup vs baseline: 3.0265x; 1.3875x over previous
//
#include <hip/hip_runtime.h>
#include <stdint.h>

#define BATCH 8
#define CIN   128
#define HH    192
#define WW    192
#define HW    (HH*WW)       // 36864
#define PXB   576           // (HW/64) pixel-tiles per batch
#define CH    2             // channels per corr block

typedef _Float16 half_t;
typedef _Float16 f16x8 __attribute__((ext_vector_type(8)));
typedef float    f32x4 __attribute__((ext_vector_type(4)));

// ---------------------------------------------------------------------------
// Fused LayerNorm(channel) + 1x1 conv (GEMM) via MFMA f16.
// ---------------------------------------------------------------------------
template<int OC>
__global__ __launch_bounds__(256)
void ln_gemm_kernel(const float* __restrict__ x,
                    const float* __restrict__ lnw, const float* __restrict__ lnb,
                    const float* __restrict__ w,   const float* __restrict__ wb,
                    half_t* __restrict__ out)
{
    __shared__ __attribute__((aligned(16))) half_t As[64][136];
    __shared__ __attribute__((aligned(16))) half_t Wsh[64][136];
    __shared__ float  redA[4][64];
    __shared__ float  redB[4][64];
    __shared__ float  mu_s[64], rs_s[64];

    const int tid = threadIdx.x;
    const int px  = tid & 63;
    const int g   = tid >> 6;
    const int l   = tid & 63;
    const int wv  = tid >> 6;

    const long p0  = (long)blockIdx.x * 64;
    const int  b   = (int)(p0 / HW);
    const int  hw0 = (int)(p0 - (long)b * HW);

    const float* xb = x + (size_t)b * CIN * HW + hw0 + px;
    float vals[32];
    float s1 = 0.f, s2 = 0.f;
#pragma unroll
    for (int j = 0; j < 32; ++j) {
        float v = xb[(size_t)(g * 32 + j) * HW];
        vals[j] = v; s1 += v; s2 += v * v;
    }
    redA[g][px] = s1; redB[g][px] = s2;
    __syncthreads();
    if (tid < 64) {
        float su = redA[0][tid] + redA[1][tid] + redA[2][tid] + redA[3][tid];
        float sq = redB[0][tid] + redB[1][tid] + redB[2][tid] + redB[3][tid];
        float mu  = su * (1.f / 128.f);
        float var = sq * (1.f / 128.f) - mu * mu;
        mu_s[tid] = mu;
        rs_s[tid] = rsqrtf(var + 1e-5f);
    }
    __syncthreads();
    {
        float mu = mu_s[px], rs = rs_s[px];
#pragma unroll
        for (int j = 0; j < 32; ++j) {
            int c = g * 32 + j;
            float a = (vals[j] - mu) * rs * lnw[c] + lnb[c];
            As[px][c] = (half_t)a;
        }
    }

    for (int nc = 0; nc < OC / 64; ++nc) {
        const int n0 = nc * 64;
#pragma unroll
        for (int i = 0; i < 8; ++i) {
            int f  = i * 256 + tid;
            int n  = f >> 5;
            int kq = (f & 31) << 2;
            const float4 wvv = *(const float4*)&w[(size_t)(n0 + n) * CIN + kq];
            Wsh[n][kq]     = (half_t)wvv.x;
            Wsh[n][kq + 1] = (half_t)wvv.y;
            Wsh[n][kq + 2] = (half_t)wvv.z;
            Wsh[n][kq + 3] = (half_t)wvv.w;
        }
        __syncthreads();

        f16x8 af[4];
#pragma unroll
        for (int kt = 0; kt < 4; ++kt)
            af[kt] = *(const f16x8*)&Wsh[wv * 16 + (l & 15)][kt * 32 + (l >> 4) * 8];

#pragma unroll
        for (int pt = 0; pt < 4; ++pt) {
            f32x4 acc = {0.f, 0.f, 0.f, 0.f};
#pragma unroll
            for (int kt = 0; kt < 4; ++kt) {
                f16x8 bfv = *(const f16x8*)&As[pt * 16 + (l & 15)][kt * 32 + (l >> 4) * 8];
                acc = __builtin_amdgcn_mfma_f32_16x16x32_f16(af[kt], bfv, acc, 0, 0, 0);
            }
#pragma unroll
            for (int r = 0; r < 4; ++r) {
                int n  = n0 + wv * 16 + (l >> 4) * 4 + r;
                int po = pt * 16 + (l & 15);
                float v = acc[r] + wb[n];
                out[((size_t)b * OC + n) * HW + hw0 + po] = (half_t)v;
            }
        }
        __syncthreads();
    }
}

// ---------------------------------------------------------------------------
// Strip-based fused: dwconv(q), dwconv(k), dwconv(v) + per-patch circular
// conv. Block = (lb, patch-row ph, CH=2 channels).
//   raw[a] a=0,1: q ch0/1; a=2,3: k ch0/1; a=4,5: v ch0/1.
//   stage A: coalesced f16x8 strip loads (10 rows x 192 cols + halo)
//   stage B: dwconv3x3; q/k -> LDS qkd, v -> global vd (f16x8 stores)
//   stage C: circular conv per (c, pw, u) from qkd.
// LDS = 37.4 KB -> 4 blocks/CU.
// ---------------------------------------------------------------------------
__global__ __launch_bounds__(256)
void corr_strip_kernel(const half_t* __restrict__ q1, const half_t* __restrict__ kv1,
                       const float* __restrict__ qw, const float* __restrict__ qb,
                       const float* __restrict__ kw, const float* __restrict__ kb,
                       half_t* __restrict__ corr, half_t* __restrict__ vd)
{
    __shared__ __attribute__((aligned(16))) half_t raw[6][10][208];
    __shared__ __attribute__((aligned(16))) half_t qkd[4][8][208];

    const int bid = blockIdx.x;
    const int cg  = bid & 127;          // 128 channel-groups of CH=2
    const int ph  = (bid >> 7) % 24;
    const int lb  = (bid >> 7) / 24;
    const int c0  = cg * CH;
    const int tid = threadIdx.x;

    // ---- zero the column-halo slots (cols 0..7 and 200..207) ----
    if (tid < 120) {
        int side = tid & 1;
        int row  = (tid >> 1) % 10;
        int a    = tid / 20;            // 0..5
        f16x8 z = {};
        *(f16x8*)&raw[a][row][side ? 200 : 0] = z;
    }

    // ---- stage A: coalesced strip loads (rows ph*8-1 .. ph*8+8) ----
    for (int i = 0; i < 6; ++i) {
        int idx = tid + 256 * i;        // 1440 vector-loads total
        if (idx >= 1440) break;
        int vec = idx % 24;             // col group (8 cols)
        int row = (idx / 24) % 10;
        int a   = idx / 240;            // 0..5
        int ch  = a & 1;
        int gh  = ph * 8 - 1 + row;
        f16x8 v = {};
        if (gh >= 0 && gh < HH) {
            const half_t* src;
            if (a < 2)      src = q1  + ((size_t)lb * 256 + c0 + ch) * HW;
            else if (a < 4) src = kv1 + ((size_t)lb * 512 + c0 + ch) * HW;
            else            src = kv1 + ((size_t)lb * 512 + 256 + c0 + ch) * HW;
            v = *(const f16x8*)&src[(size_t)gh * WW + vec * 8];
        }
        *(f16x8*)&raw[a][row][8 + vec * 8] = v;
    }
    __syncthreads();

    // ---- stage B: depthwise 3x3; 1152 units = (a, u, xg) ----
    for (int i = 0; i < 5; ++i) {
        int unit = tid + 256 * i;
        if (unit >= 1152) break;
        int xg = unit % 24;
        int u  = (unit / 24) % 8;
        int a  = unit / 192;            // 0..5
        int ch = a & 1;
        const half_t (*rw)[208] = raw[a];
        const float* wt;
        float bias;
        if (a < 2)      { wt = qw + (size_t)(c0 + ch) * 9;       bias = qb[c0 + ch]; }
        else if (a < 4) { wt = kw + (size_t)(c0 + ch) * 9;       bias = kb[c0 + ch]; }
        else            { wt = kw + (size_t)(256 + c0 + ch) * 9; bias = kb[256 + c0 + ch]; }
        int x0 = xg * 8;
        float r0[10], r1[10], r2[10];
#pragma unroll
        for (int j = 0; j < 10; ++j) {
            r0[j] = (float)rw[u + 0][7 + x0 + j];
            r1[j] = (float)rw[u + 1][7 + x0 + j];
            r2[j] = (float)rw[u + 2][7 + x0 + j];
        }
        float acc[8];
#pragma unroll
        for (int xx = 0; xx < 8; ++xx) acc[xx] = bias;
#pragma unroll
        for (int dx = 0; dx < 3; ++dx) {
            float w0 = wt[dx], w1 = wt[3 + dx], w2 = wt[6 + dx];
#pragma unroll
            for (int xx = 0; xx < 8; ++xx) {
                acc[xx] += r0[xx + dx] * w0 + r1[xx + dx] * w1 + r2[xx + dx] * w2;
            }
        }
        f16x8 o;
#pragma unroll
        for (int xx = 0; xx < 8; ++xx) o[xx] = (half_t)acc[xx];
        if (a < 4) {
            *(f16x8*)&qkd[a][u][x0] = o;
        } else {
            *(f16x8*)&vd[((size_t)lb * 256 + c0 + ch) * HW + (size_t)(ph * 8 + u) * WW + x0] = o;
        }
    }
    __syncthreads();

    // ---- stage C: per-patch circular conv ----
    for (int i = 0; i < 2; ++i) {
        int unit = tid + 256 * i;       // 384 units: (c, pw, u)
        if (unit >= 384) break;
        int c   = unit / 192;
        int rem = unit % 192;
        int pw  = rem >> 3;
        int u   = rem & 7;
        float acc[8];
#pragma unroll
        for (int v = 0; v < 8; ++v) acc[v] = 0.f;
#pragma unroll
        for (int s = 0; s < 8; ++s) {
            f16x8 qv8 = *(const f16x8*)&qkd[c][s][pw * 8];
            f16x8 kv8 = *(const f16x8*)&qkd[2 + c][(u - s) & 7][pw * 8];
            float qv[8], kr2[16];
#pragma unroll
            for (int t = 0; t < 8; ++t) {
                qv[t] = (float)qv8[t];
                float kvf = (float)kv8[t];
                kr2[t] = kvf; kr2[t + 8] = kvf;
            }
#pragma unroll
            for (int t = 0; t < 8; ++t)
#pragma unroll
                for (int v = 0; v < 8; ++v)
                    acc[v] += qv[t] * kr2[8 - t + v];
        }
        f16x8 ov;
#pragma unroll
        for (int v = 0; v < 8; ++v) ov[v] = (half_t)acc[v];
        *(f16x8*)&corr[((size_t)lb * 256 + c0 + c) * HW + (size_t)(ph * 8 + u) * WW + pw * 8] = ov;
    }
}

// ---------------------------------------------------------------------------
// Fused LN(corr)*vd + 1x1 proj GEMM (K=256 split in 2, N=128) -> f32 out.
// ---------------------------------------------------------------------------
__global__ __launch_bounds__(256)
void proj_kernel(const half_t* __restrict__ corr, const half_t* __restrict__ vd,
                 const float* __restrict__ lnw, const float* __restrict__ lnb,
                 const float* __restrict__ w,   const float* __restrict__ wb,
                 float* __restrict__ out)
{
    __shared__ __attribute__((aligned(16))) half_t As[64][136];
    __shared__ __attribute__((aligned(16))) half_t Wsh[128][136];
    __shared__ float  redA[4][64];
    __shared__ float  redB[4][64];
    __shared__ float  mu_s[64], rs_s[64];

    const int tid = threadIdx.x;
    const int px  = tid & 63;
    const int g   = tid >> 6;
    const int l   = tid & 63;
    const int wv  = tid >> 6;

    const long p0  = (long)blockIdx.x * 64;
    const int  lb  = (int)(p0 / HW);
    const int  hw0 = (int)(p0 - (long)lb * HW);

    const half_t* cb = corr + (size_t)lb * 256 * HW + hw0 + px;
    const half_t* vb = vd   + (size_t)lb * 256 * HW + hw0 + px;

    float s1 = 0.f, s2 = 0.f;
#pragma unroll 8
    for (int j = 0; j < 64; ++j) {
        float cv = (float)cb[(size_t)(g * 64 + j) * HW];
        s1 += cv; s2 += cv * cv;
    }
    redA[g][px] = s1; redB[g][px] = s2;
    __syncthreads();
    if (tid < 64) {
        float su = redA[0][tid] + redA[1][tid] + redA[2][tid] + redA[3][tid];
        float sq = redB[0][tid] + redB[1][tid] + redB[2][tid] + redB[3][tid];
        float mu  = su * (1.f / 256.f);
        float var = sq * (1.f / 256.f) - mu * mu;
        mu_s[tid] = mu;
        rs_s[tid] = rsqrtf(var + 1e-5f);
    }
    __syncthreads();
    const float mu = mu_s[px], rs = rs_s[px];

    f32x4 acc[2][4];
#pragma unroll
    for (int nt = 0; nt < 2; ++nt)
#pragma unroll
        for (int pt = 0; pt < 4; ++pt) acc[nt][pt] = {0.f, 0.f, 0.f, 0.f};

    for (int kc = 0; kc < 2; ++kc) {
#pragma unroll 4
        for (int j = 0; j < 32; ++j) {
            int cl = g * 32 + j;
            int c  = kc * 128 + cl;
            float cv = (float)cb[(size_t)c * HW];
            float vv = (float)vb[(size_t)c * HW];
            As[px][cl] = (half_t)(((cv - mu) * rs * lnw[c] + lnb[c]) * vv);
        }
#pragma unroll
        for (int i = 0; i < 16; ++i) {
            int f  = i * 256 + tid;
            int n  = f >> 5;
            int kq = (f & 31) << 2;
            const float4 wvv = *(const float4*)&w[(size_t)n * 256 + kc * 128 + kq];
            Wsh[n][kq]     = (half_t)wvv.x;
            Wsh[n][kq + 1] = (half_t)wvv.y;
            Wsh[n][kq + 2] = (half_t)wvv.z;
            Wsh[n][kq + 3] = (half_t)wvv.w;
        }
        __syncthreads();

#pragma unroll
        for (int nt = 0; nt < 2; ++nt) {
            f16x8 af[4];
#pragma unroll
            for (int kt = 0; kt < 4; ++kt)
                af[kt] = *(const f16x8*)&Wsh[wv * 32 + nt * 16 + (l & 15)][kt * 32 + (l >> 4) * 8];
#pragma unroll
            for (int pt = 0; pt < 4; ++pt) {
#pragma unroll
                for (int kt = 0; kt < 4; ++kt) {
                    f16x8 bfv = *(const f16x8*)&As[pt * 16 + (l & 15)][kt * 32 + (l >> 4) * 8];
                    acc[nt][pt] = __builtin_amdgcn_mfma_f32_16x16x32_f16(af[kt], bfv, acc[nt][pt], 0, 0, 0);
                }
            }
        }
        __syncthreads();
    }

#pragma unroll
    for (int nt = 0; nt < 2; ++nt)
#pragma unroll
        for (int pt = 0; pt < 4; ++pt)
#pragma unroll
            for (int r = 0; r < 4; ++r) {
                int n  = wv * 32 + nt * 16 + (l >> 4) * 4 + r;
                int po = pt * 16 + (l & 15);
                out[((size_t)lb * 128 + n) * HW + hw0 + po] = acc[nt][pt][r] + wb[n];
            }
}

// ---------------------------------------------------------------------------
extern "C" void kernel_launch(void* const* d_in, const int* in_sizes, int n_in,
                              void* d_out, int out_size, void* d_ws, size_t ws_size,
                              hipStream_t stream)
{
    const float* x        = (const float*)d_in[0];
    const float* evt      = (const float*)d_in[1];
    const float* ln_img_w = (const float*)d_in[2];
    const float* ln_img_b = (const float*)d_in[3];
    const float* ln_evt_w = (const float*)d_in[4];
    const float* ln_evt_b = (const float*)d_in[5];
    const float* q_w      = (const float*)d_in[6];
    const float* q_b      = (const float*)d_in[7];
    const float* q_dw_w   = (const float*)d_in[8];
    const float* q_dw_b   = (const float*)d_in[9];
    const float* kv_w     = (const float*)d_in[10];
    const float* kv_b     = (const float*)d_in[11];
    const float* kv_dw_w  = (const float*)d_in[12];
    const float* kv_dw_b  = (const float*)d_in[13];
    const float* ln_corr_w= (const float*)d_in[14];
    const float* ln_corr_b= (const float*)d_in[15];
    const float* proj_w   = (const float*)d_in[16];
    const float* proj_b   = (const float*)d_in[17];
    float* out = (float*)d_out;

    const size_t per_b = (size_t)(256 + 512 + 256 + 256) * HW * sizeof(half_t); // 94.4 MB
    int PB = 1;
    if      (ws_size >= 8 * per_b) PB = 8;
    else if (ws_size >= 4 * per_b) PB = 4;
    else if (ws_size >= 2 * per_b) PB = 2;

    half_t* q1   = (half_t*)d_ws;
    half_t* kv1  = q1  + (size_t)PB * 256 * HW;
    half_t* vd   = kv1 + (size_t)PB * 512 * HW;
    half_t* corr = vd  + (size_t)PB * 256 * HW;

    dim3 blk(256);
    for (int b0 = 0; b0 < BATCH; b0 += PB) {
        int nb = PB;
        ln_gemm_kernel<256><<<nb * PXB, blk, 0, stream>>>(
            x + (size_t)b0 * CIN * HW, ln_img_w, ln_img_b, q_w, q_b, q1);
        ln_gemm_kernel<512><<<nb * PXB, blk, 0, stream>>>(
            evt + (size_t)b0 * CIN * HW, ln_evt_w, ln_evt_b, kv_w, kv_b, kv1);
        corr_strip_kernel<<<nb * 24 * 128, blk, 0, stream>>>(
            q1, kv1, q_dw_w, q_dw_b, kv_dw_w, kv_dw_b, corr, vd);
        proj_kernel<<<nb * PXB, blk, 0, stream>>>(
            corr, vd, ln_corr_w, ln_corr_b, proj_w, proj_b,
            out + (size_t)b0 * 128 * HW);
    }
}